// Round 24
// baseline (162.969 us; speedup 1.0000x reference)
//
#include <hip/hip_runtime.h>
#include <float.h>

#define N_PTS 6144
#define D_IN  512
#define H1_DIM 256
#define H2_DIM 128
#define G_DIM  64
#define KNN    32
#define NOUT   22
#define NQ     (N_PTS / 4)

typedef short s8v __attribute__((ext_vector_type(8)));   // 8 bf16 in 4 VGPR
typedef float f32x4 __attribute__((ext_vector_type(4)));
typedef unsigned u32x4 __attribute__((ext_vector_type(4)));
typedef unsigned short u16;
typedef unsigned short u16x4 __attribute__((ext_vector_type(4)));
typedef unsigned long long u64;

__device__ __forceinline__ u16 f2bf(float f) {
  unsigned u = __float_as_uint(f);
  u += 0x7FFFu + ((u >> 16) & 1u);          // RNE to bf16
  return (u16)(u >> 16);
}
__device__ __forceinline__ float bf2f(u16 s) {
  return __uint_as_float(((unsigned)s) << 16);
}
__device__ __forceinline__ void split3(float v, u16& a0, u16& a1, u16& a2) {
  a0 = f2bf(v);
  float r1 = v - bf2f(a0);
  a1 = f2bf(r1);
  a2 = f2bf(r1 - bf2f(a1));
}
__device__ __forceinline__ unsigned sortkey(float f) {
  unsigned ub = __float_as_uint(f);
  return (ub & 0x80000000u) ? ~ub : (ub | 0x80000000u);
}

// ---------------------------------------------------------------------------
// Generic MFMA GEMM (MLP path), 3-way bf16 split, 6-term schedule.
// ---------------------------------------------------------------------------
template<int BM, bool AF32, bool SPLITK, bool BIAS, bool RELU, bool WF32, bool WSPLIT>
__global__ __launch_bounds__(256, 4) void mfma_gemm(
    const void* __restrict__ A0any, const u16* __restrict__ A1_, const u16* __restrict__ A2_,
    const u16* __restrict__ B0_, const u16* __restrict__ B1_, const u16* __restrict__ B2_,
    const float* __restrict__ bias,
    float* __restrict__ Cf, u16* __restrict__ C0, u16* __restrict__ C1, u16* __restrict__ C2,
    int Ktot, int Ks, int ldC, size_t MN)
{
  const int MT = BM / 32, NT = 2;
  const int APL = BM * 32;
  const int BBASE = 3 * APL;
  __shared__ u16 lds[(BM + 64) * 32 * 3];

  const int t = threadIdx.x;
  const int lane = t & 63, wave = t >> 6;
  const int wm = wave >> 1, wn = wave & 1;
  const int m0 = blockIdx.y * BM, n0 = blockIdx.x * 64;
  const int kz = blockIdx.z * Ks;

  f32x4 acc[MT][NT] = {};

  const int pA = BM / 16;
  const int NC = 3 * pA + 12;

  for (int k0 = 0; k0 < Ks; k0 += 32) {
    if (k0) __syncthreads();
    const int kb = kz + k0;
    if (AF32) {
      const float* A = (const float*)A0any;
      #pragma unroll
      for (int c0 = 0; c0 < BM * 4; c0 += 256) {
        int c = c0 + t;
        int row = c >> 2, slot = c & 3;
        const float* g = A + (size_t)(m0 + row) * Ktot + kb + slot * 8;
        f32x4 fa = *(const f32x4*)g;
        f32x4 fb = *(const f32x4*)(g + 4);
        int dst = row * 32 + ((slot ^ ((row >> 1) & 3)) << 3);
        s8v v0, v1, v2;
        #pragma unroll
        for (int e = 0; e < 4; ++e) {
          u16 a0, a1, a2; split3(fa[e], a0, a1, a2);
          v0[e] = (short)a0; v1[e] = (short)a1; v2[e] = (short)a2;
        }
        #pragma unroll
        for (int e = 0; e < 4; ++e) {
          u16 a0, a1, a2; split3(fb[e], a0, a1, a2);
          v0[4 + e] = (short)a0; v1[4 + e] = (short)a1; v2[4 + e] = (short)a2;
        }
        *(s8v*)(lds + dst) = v0;
        *(s8v*)(lds + APL + dst) = v1;
        *(s8v*)(lds + 2 * APL + dst) = v2;
      }
      for (int c = wave; c < 12; c += 4) {
        int p = c >> 2, lc = c & 3;
        int row = lc * 16 + (lane >> 2);
        int srcslot = (lane & 3) ^ ((row >> 1) & 3);
        const u16* src = (p == 0) ? B0_ : (p == 1) ? B1_ : B2_;
        const u16* g = src + (size_t)(n0 + row) * Ktot + kb + srcslot * 8;
        __builtin_amdgcn_global_load_lds(
            (const __attribute__((address_space(1))) unsigned*)g,
            (__attribute__((address_space(3))) unsigned*)(lds + BBASE + p * 2048 + lc * 512),
            16, 0, 0);
      }
    } else {
      for (int c = wave; c < NC; c += 4) {
        const u16* src; int dstoff; int row0; int lc;
        if (c < 3 * pA) {
          int p = c / pA; lc = c % pA;
          src = (p == 0) ? (const u16*)A0any : (p == 1) ? A1_ : A2_;
          dstoff = p * APL + lc * 512;
          row0 = m0;
        } else {
          int cb = c - 3 * pA;
          int p = cb >> 2; lc = cb & 3;
          src = (p == 0) ? B0_ : (p == 1) ? B1_ : B2_;
          dstoff = BBASE + p * 2048 + lc * 512;
          row0 = n0;
        }
        int row = lc * 16 + (lane >> 2);
        int srcslot = (lane & 3) ^ ((row >> 1) & 3);
        const u16* g = src + (size_t)(row0 + row) * Ktot + kb + srcslot * 8;
        __builtin_amdgcn_global_load_lds(
            (const __attribute__((address_space(1))) unsigned*)g,
            (__attribute__((address_space(3))) unsigned*)(lds + dstoff),
            16, 0, 0);
      }
    }
    __syncthreads();

    s8v af[3][MT], bf[3][NT];
    #pragma unroll
    for (int mt = 0; mt < MT; ++mt) {
      int r = wm * (BM / 2) + mt * 16 + (lane & 15);
      int off = r * 32 + (((lane >> 4) ^ ((r >> 1) & 3)) << 3);
      #pragma unroll
      for (int p = 0; p < 3; ++p) af[p][mt] = *(const s8v*)(lds + p * APL + off);
    }
    #pragma unroll
    for (int nt = 0; nt < NT; ++nt) {
      int r = wn * 32 + nt * 16 + (lane & 15);
      int off = r * 32 + (((lane >> 4) ^ ((r >> 1) & 3)) << 3);
      #pragma unroll
      for (int p = 0; p < 3; ++p) bf[p][nt] = *(const s8v*)(lds + BBASE + p * 2048 + off);
    }
    #pragma unroll
    for (int mt = 0; mt < MT; ++mt)
      #pragma unroll
      for (int nt = 0; nt < NT; ++nt) {
        f32x4 a = acc[mt][nt];
        a = __builtin_amdgcn_mfma_f32_16x16x32_bf16(af[0][mt], bf[0][nt], a, 0, 0, 0);
        a = __builtin_amdgcn_mfma_f32_16x16x32_bf16(af[0][mt], bf[1][nt], a, 0, 0, 0);
        a = __builtin_amdgcn_mfma_f32_16x16x32_bf16(af[1][mt], bf[0][nt], a, 0, 0, 0);
        a = __builtin_amdgcn_mfma_f32_16x16x32_bf16(af[1][mt], bf[1][nt], a, 0, 0, 0);
        a = __builtin_amdgcn_mfma_f32_16x16x32_bf16(af[0][mt], bf[2][nt], a, 0, 0, 0);
        a = __builtin_amdgcn_mfma_f32_16x16x32_bf16(af[2][mt], bf[0][nt], a, 0, 0, 0);
        acc[mt][nt] = a;
      }
  }

  #pragma unroll
  for (int mt = 0; mt < MT; ++mt) {
    #pragma unroll
    for (int nt = 0; nt < NT; ++nt) {
      int col = n0 + wn * 32 + nt * 16 + (lane & 15);
      float bv = (BIAS && !SPLITK) ? bias[col] : 0.f;
      #pragma unroll
      for (int v = 0; v < 4; ++v) {
        int row = m0 + wm * (BM / 2) + mt * 16 + (lane >> 4) * 4 + v;
        float val = acc[mt][nt][v] + bv;
        size_t o = (size_t)row * ldC + col;
        if (SPLITK) {
          Cf[(size_t)blockIdx.z * MN + o] = val;
        } else {
          if (RELU) val = fmaxf(val, 0.f);
          if (WF32) Cf[o] = val;
          if (WSPLIT) {
            u16 a0, a1, a2; split3(val, a0, a1, a2);
            C0[o] = a0; C1[o] = a1; C2[o] = a2;
          }
        }
      }
    }
  }
}

// ---------------------------------------------------------------------------
// Symmetric Gram, 128x128 tile, 512 threads (8 waves, 2x4). u16-key epilogue
// + quad-min array Qm. Upper-triangle blocks only; mirror for x>y.
// ---------------------------------------------------------------------------
__global__ __launch_bounds__(512, 4) void gram_symm(
    const u16* __restrict__ A0, const u16* __restrict__ A1, const u16* __restrict__ A2,
    const float* __restrict__ sq, u16* __restrict__ Ck, u16* __restrict__ Qm, int ldC)
{
  if ((int)blockIdx.x < (int)blockIdx.y) return;
  const int MT = 4, NT = 2;
  __shared__ u16 lds[2 * 128 * 32 * 3];          // 48 KB

  const int t = threadIdx.x;
  const int lane = t & 63, wave = t >> 6;
  const int wm = wave >> 2, wn = wave & 3;
  const int m0 = blockIdx.y * 128, n0 = blockIdx.x * 128;
  const bool mirror = (int)blockIdx.x > (int)blockIdx.y;

  f32x4 acc[MT][NT] = {};

  for (int k0 = 0; k0 < H2_DIM; k0 += 32) {
    if (k0) __syncthreads();
    for (int c = wave; c < 48; c += 8) {
      int half = c >= 24;
      int cb = half ? c - 24 : c;
      int p = cb >> 3, lc = cb & 7;
      const u16* src = (p == 0) ? A0 : (p == 1) ? A1 : A2;
      int dstoff = half * 12288 + p * 4096 + lc * 512;
      int row0 = half ? n0 : m0;
      int row = lc * 16 + (lane >> 2);
      int srcslot = (lane & 3) ^ ((row >> 1) & 3);
      const u16* g = src + (size_t)(row0 + row) * H2_DIM + k0 + srcslot * 8;
      __builtin_amdgcn_global_load_lds(
          (const __attribute__((address_space(1))) unsigned*)g,
          (__attribute__((address_space(3))) unsigned*)(lds + dstoff),
          16, 0, 0);
    }
    __syncthreads();

    s8v af[3][MT], bf[3][NT];
    #pragma unroll
    for (int mt = 0; mt < MT; ++mt) {
      int r = wm * 64 + mt * 16 + (lane & 15);
      int off = r * 32 + (((lane >> 4) ^ ((r >> 1) & 3)) << 3);
      #pragma unroll
      for (int p = 0; p < 3; ++p) af[p][mt] = *(const s8v*)(lds + p * 4096 + off);
    }
    #pragma unroll
    for (int nt = 0; nt < NT; ++nt) {
      int r = wn * 32 + nt * 16 + (lane & 15);
      int off = r * 32 + (((lane >> 4) ^ ((r >> 1) & 3)) << 3);
      #pragma unroll
      for (int p = 0; p < 3; ++p) bf[p][nt] = *(const s8v*)(lds + 12288 + p * 4096 + off);
    }
    #pragma unroll
    for (int mt = 0; mt < MT; ++mt)
      #pragma unroll
      for (int nt = 0; nt < NT; ++nt) {
        f32x4 a = acc[mt][nt];
        a = __builtin_amdgcn_mfma_f32_16x16x32_bf16(af[0][mt], bf[0][nt], a, 0, 0, 0);
        a = __builtin_amdgcn_mfma_f32_16x16x32_bf16(af[0][mt], bf[1][nt], a, 0, 0, 0);
        a = __builtin_amdgcn_mfma_f32_16x16x32_bf16(af[1][mt], bf[0][nt], a, 0, 0, 0);
        a = __builtin_amdgcn_mfma_f32_16x16x32_bf16(af[1][mt], bf[1][nt], a, 0, 0, 0);
        a = __builtin_amdgcn_mfma_f32_16x16x32_bf16(af[0][mt], bf[2][nt], a, 0, 0, 0);
        a = __builtin_amdgcn_mfma_f32_16x16x32_bf16(af[2][mt], bf[0][nt], a, 0, 0, 0);
        acc[mt][nt] = a;
      }
  }

  unsigned mk32[MT][NT][2];
  __syncthreads();
  u16* stD = lds;
  #pragma unroll
  for (int mt = 0; mt < MT; ++mt) {
    #pragma unroll
    for (int nt = 0; nt < NT; ++nt) {
      int cl = wn * 32 + nt * 16 + (lane & 15);
      float sqc = sq[n0 + cl];
      #pragma unroll
      for (int v = 0; v < 4; ++v) {
        int rl = wm * 64 + mt * 16 + (lane >> 4) * 4 + v;
        float val = acc[mt][nt][v];
        float f = fmaf(-2.f, val, sqc);
        unsigned uu = sortkey(f);
        if (m0 + rl == n0 + cl) uu = 0xFFFFFFFFu;
        stD[rl * 136 + cl] = (u16)(uu >> 16);
        if (mirror) {
          unsigned km = sortkey(fmaf(-2.f, val, sq[m0 + rl])) >> 16;
          if (v & 1) mk32[mt][nt][v >> 1] |= km << 16;
          else       mk32[mt][nt][v >> 1] = km;
        }
      }
    }
  }
  __syncthreads();
  for (int e = t; e < 128 * 16; e += 512) {
    int row = e >> 4, ch = e & 15;
    u32x4 vv = *(const u32x4*)(stD + row * 136 + ch * 8);
    *(u32x4*)(Ck + (size_t)(m0 + row) * ldC + n0 + ch * 8) = vv;
  }
  for (int e = t; e < 128 * 32; e += 512) {
    int row = e >> 5, qg = e & 31;
    const u16* p = stD + row * 136 + qg * 4;
    u16 a = p[0] < p[1] ? p[0] : p[1];
    u16 b = p[2] < p[3] ? p[2] : p[3];
    Qm[(size_t)(m0 + row) * NQ + (n0 >> 2) + qg] = a < b ? a : b;
  }
  if (mirror) {
    __syncthreads();
    u16* stM = lds;
    #pragma unroll
    for (int mt = 0; mt < MT; ++mt) {
      #pragma unroll
      for (int nt = 0; nt < NT; ++nt) {
        int cl = wn * 32 + nt * 16 + (lane & 15);
        #pragma unroll
        for (int v = 0; v < 4; ++v) {
          int rl = wm * 64 + mt * 16 + (lane >> 4) * 4 + v;
          unsigned km = (v & 1) ? (mk32[mt][nt][v >> 1] >> 16)
                                : (mk32[mt][nt][v >> 1] & 0xFFFFu);
          stM[cl * 136 + rl] = (u16)km;
        }
      }
    }
    __syncthreads();
    for (int e = t; e < 128 * 16; e += 512) {
      int row = e >> 4, ch = e & 15;
      u32x4 vv = *(const u32x4*)(stM + row * 136 + ch * 8);
      *(u32x4*)(Ck + (size_t)(n0 + row) * ldC + m0 + ch * 8) = vv;
    }
    for (int e = t; e < 128 * 32; e += 512) {
      int row = e >> 5, qg = e & 31;
      const u16* p = stM + row * 136 + qg * 4;
      u16 a = p[0] < p[1] ? p[0] : p[1];
      u16 b = p[2] < p[3] ? p[2] : p[3];
      Qm[(size_t)(n0 + row) * NQ + (m0 >> 2) + qg] = a < b ? a : b;
    }
  }
}

template<int S, bool BIAS, bool RELU, bool WF32, bool WSPLIT>
__global__ void combine(const float* __restrict__ P, const float* __restrict__ bias,
                        size_t MN, int Ncols,
                        float* __restrict__ Cf, u16* __restrict__ C0,
                        u16* __restrict__ C1, u16* __restrict__ C2)
{
  size_t idx = ((size_t)blockIdx.x * 256 + threadIdx.x) * 4;
  if (idx >= MN) return;
  f32x4 s = *(const f32x4*)(P + idx);
  #pragma unroll
  for (int z = 1; z < S; ++z) s += *(const f32x4*)(P + (size_t)z * MN + idx);
  int n = (int)(idx % (size_t)Ncols);
  #pragma unroll
  for (int e = 0; e < 4; ++e) {
    float v = s[e] + (BIAS ? bias[n + e] : 0.f);
    if (RELU) v = fmaxf(v, 0.f);
    if (WF32) Cf[idx + e] = v;
    if (WSPLIT) {
      u16 a0, a1, a2; split3(v, a0, a1, a2);
      C0[idx + e] = a0; C1[idx + e] = a1; C2[idx + e] = a2;
    }
  }
}

__global__ void prep_all(const float* __restrict__ W0, u16* __restrict__ a0,
                         u16* __restrict__ a1, u16* __restrict__ a2,
                         const float* __restrict__ W1, u16* __restrict__ b0,
                         u16* __restrict__ b1, u16* __restrict__ b2,
                         const float* __restrict__ gW, u16* __restrict__ c0,
                         u16* __restrict__ c1, u16* __restrict__ c2,
                         const float* __restrict__ cW, const float* __restrict__ cb,
                         const float* __restrict__ dW, const float* __restrict__ db,
                         float* __restrict__ Wc, float* __restrict__ bc)
{
  int id = blockIdx.x * 256 + threadIdx.x;
  const int S0 = D_IN * H1_DIM, S1 = H1_DIM * H2_DIM, S2 = H2_DIM * G_DIM;
  const int SW = S0 + S1 + S2;
  if (id < SW) {
    const float* W; u16 *p0, *p1, *p2; int K, N;
    if (id < S0)           { W = W0; p0 = a0; p1 = a1; p2 = a2; K = D_IN;   N = H1_DIM; }
    else if (id < S0 + S1) { id -= S0; W = W1; p0 = b0; p1 = b1; p2 = b2; K = H1_DIM; N = H2_DIM; }
    else                   { id -= S0 + S1; W = gW; p0 = c0; p1 = c1; p2 = c2; K = H2_DIM; N = G_DIM; }
    int k = id / N, n = id % N;
    u16 x0, x1, x2;
    split3(W[id], x0, x1, x2);
    size_t o = (size_t)n * K + k;
    p0[o] = x0; p1[o] = x1; p2[o] = x2;
    return;
  }
  id -= SW;
  if (id < 64 * NOUT) {
    int g = id / NOUT, c = id % NOUT;
    float s = 0.f;
    if (c < 16) {
      for (int r = 0; r < 8; ++r) s += cW[(r * 64 + g) * 16 + c];
    } else {
      int k = (c - 16) >> 1, o = (c - 16) & 1;
      for (int r = 0; r < 8; ++r) s += dW[k * 1024 + (r * 64 + g) * 2 + o];
    }
    Wc[id] = s;
    if (g == 0) bc[c] = (c < 16) ? cb[c] : db[c - 16];
  }
}

__global__ void row_stats(const float* __restrict__ h, const float* __restrict__ Wh,
                          const float* __restrict__ ga, float* __restrict__ sq,
                          float* __restrict__ f1, float* __restrict__ f2)
{
  int i = blockIdx.x * 256 + threadIdx.x;
  const float* hr = h + (size_t)i * H2_DIM;
  float s = 0.f;
  for (int k = 0; k < H2_DIM; ++k) { float v = hr[k]; s = fmaf(v, v, s); }
  sq[i] = s;
  const float* wr = Wh + (size_t)i * G_DIM;
  float a = 0.f, b = 0.f;
  for (int g = 0; g < G_DIM; ++g) {
    float w = wr[g];
    a = fmaf(w, ga[g], a);
    b = fmaf(w, ga[G_DIM + g], b);
  }
  f1[i] = a; f2[i] = b;
}

// ---------------------------------------------------------------------------
// u16-key topk, TWO independent rows per wave (ILP for latency hiding).
// Per row: r23-proven pipeline (quad-min bisection -> collect -> key bisection
// -> classify (set semantics) -> exact fp32 tie-refine + 128-bitonic).
// ---------------------------------------------------------------------------
__global__ __launch_bounds__(256) void topk_att(const u16* __restrict__ Sb,
    const u16* __restrict__ Qm,
    const float* __restrict__ f1, const float* __restrict__ f2,
    const float* __restrict__ Wh, const float* __restrict__ Wc, const float* __restrict__ bc,
    const float* __restrict__ sq, const float* __restrict__ hF,
    float* __restrict__ out, int m0, int nrows)
{
  const int t = threadIdx.x;
  const int lane = t & 63, wv = t >> 6;
  const int rbase = (nrows - 8 - blockIdx.x * 8) + wv * 2;   // reversed mapping
  const int i0 = m0 + rbase, i1 = i0 + 1;
  const u16* SrowA = Sb + (size_t)rbase * N_PTS;
  const u16* SrowB = SrowA + N_PTS;
  const u16* QrowA = Qm + (size_t)rbase * NQ;
  const u16* QrowB = QrowA + NQ;

  __shared__ float WcL[64 * NOUT];
  __shared__ unsigned candS[4][2][384];
  __shared__ u16 tieS[4][2][128];
  __shared__ float hiL[4][2][128];
  __shared__ int neighS[4][2][33];
  __shared__ float attS[4][2][33];
  __shared__ float hpfS[4][2][64];

  for (int idx = t; idx < 64 * NOUT; idx += 256) WcL[idx] = Wc[idx];
  __syncthreads();                       // only block barrier

  hiL[wv][0][lane]      = hF[(size_t)i0 * H2_DIM + lane];
  hiL[wv][0][64 + lane] = hF[(size_t)i0 * H2_DIM + 64 + lane];
  hiL[wv][1][lane]      = hF[(size_t)i1 * H2_DIM + lane];
  hiL[wv][1][64 + lane] = hF[(size_t)i1 * H2_DIM + 64 + lane];

  // ---- load 24 quad-mins per row ----
  unsigned q[2][24];
  #pragma unroll
  for (int g = 0; g < 6; ++g) {
    u16x4 vA = *(const u16x4*)(QrowA + (g << 8) + (lane << 2));
    u16x4 vB = *(const u16x4*)(QrowB + (g << 8) + (lane << 2));
    #pragma unroll
    for (int e = 0; e < 4; ++e) {
      q[0][g * 4 + e] = (unsigned)vA[e];
      q[1][g * 4 + e] = (unsigned)vB[e];
    }
  }
  #define QI(s) (((s >> 2) << 8) + (lane << 2) + ((s) & 3))

  unsigned mn[2], mx[2];
  #pragma unroll
  for (int r = 0; r < 2; ++r) {
    unsigned lmin = q[r][0];
    #pragma unroll
    for (int c = 1; c < 24; ++c) lmin = q[r][c] < lmin ? q[r][c] : lmin;
    mn[r] = lmin; mx[r] = lmin;
  }
  #pragma unroll
  for (int off = 32; off > 0; off >>= 1) {
    #pragma unroll
    for (int r = 0; r < 2; ++r) {
      unsigned o1 = __shfl_xor(mn[r], off); mn[r] = o1 < mn[r] ? o1 : mn[r];
      unsigned o2 = __shfl_xor(mx[r], off); mx[r] = o2 > mx[r] ? o2 : mx[r];
    }
  }

  // ---- dual bisection 1: Q[r] = exact 32nd-smallest quad-min ----
  long long lo[2], hi[2];
  #pragma unroll
  for (int r = 0; r < 2; ++r) { lo[r] = (long long)mn[r] - 1; hi[r] = (long long)mx[r]; }
  while ((hi[0] - lo[0] > 1) || (hi[1] - lo[1] > 1)) {
    unsigned mm[2][3];
    int cnt[2][3] = {};
    #pragma unroll
    for (int r = 0; r < 2; ++r) {
      long long span = hi[r] - lo[r];
      mm[r][0] = (unsigned)(lo[r] + (span >> 2));
      mm[r][1] = (unsigned)(lo[r] + (span >> 1));
      mm[r][2] = (unsigned)(hi[r] - (span >> 2));
    }
    #pragma unroll
    for (int c = 0; c < 24; ++c) {
      #pragma unroll
      for (int r = 0; r < 2; ++r) {
        cnt[r][0] += (q[r][c] <= mm[r][0]);
        cnt[r][1] += (q[r][c] <= mm[r][1]);
        cnt[r][2] += (q[r][c] <= mm[r][2]);
      }
    }
    #pragma unroll
    for (int off = 32; off > 0; off >>= 1) {
      #pragma unroll
      for (int r = 0; r < 2; ++r) {
        cnt[r][0] += __shfl_xor(cnt[r][0], off);
        cnt[r][1] += __shfl_xor(cnt[r][1], off);
        cnt[r][2] += __shfl_xor(cnt[r][2], off);
      }
    }
    #pragma unroll
    for (int r = 0; r < 2; ++r) {
      if (hi[r] - lo[r] > 1) {
        if (cnt[r][0] >= KNN)      { hi[r] = mm[r][0]; }
        else if (cnt[r][1] >= KNN) { lo[r] = mm[r][0]; hi[r] = mm[r][1]; }
        else if (cnt[r][2] >= KNN) { lo[r] = mm[r][1]; hi[r] = mm[r][2]; }
        else                       { lo[r] = mm[r][2]; }
      }
    }
  }
  const unsigned Qv0 = (unsigned)hi[0], Qv1 = (unsigned)hi[1];

  // ---- dual collect (cap 96 quads each) ----
  #pragma unroll
  for (int s = 0; s < 6; ++s) {
    candS[wv][0][lane + s * 64] = 0xFFFFFFFFu;
    candS[wv][1][lane + s * 64] = 0xFFFFFFFFu;
  }
  const u64 below = (lane == 0) ? 0ull : (~0ull >> (64 - lane));
  int qcA = 0, qcB = 0;
  #pragma unroll
  for (int s = 0; s < 24; ++s) {
    bool aA = (q[0][s] <= Qv0);
    u64 mA = __ballot(aA);
    if (aA) {
      int pos = qcA + (int)__popcll(mA & below);
      if (pos < 96) {
        int qi = QI(s);
        u16x4 v = *(const u16x4*)(SrowA + (qi << 2));
        #pragma unroll
        for (int e = 0; e < 4; ++e)
          candS[wv][0][pos * 4 + e] = ((unsigned)v[e] << 13) | (unsigned)((qi << 2) + e);
      }
    }
    qcA += (int)__popcll(mA);
    bool aB = (q[1][s] <= Qv1);
    u64 mB = __ballot(aB);
    if (aB) {
      int pos = qcB + (int)__popcll(mB & below);
      if (pos < 96) {
        int qi = QI(s);
        u16x4 v = *(const u16x4*)(SrowB + (qi << 2));
        #pragma unroll
        for (int e = 0; e < 4; ++e)
          candS[wv][1][pos * 4 + e] = ((unsigned)v[e] << 13) | (unsigned)((qi << 2) + e);
      }
    }
    qcB += (int)__popcll(mB);
  }

  unsigned ck[2][6];
  #pragma unroll
  for (int s = 0; s < 6; ++s) {
    ck[0][s] = candS[wv][0][lane + s * 64];
    ck[1][s] = candS[wv][1][lane + s * 64];
  }

  // tightened intervals from real collected keys
  unsigned kmn[2] = {0x10000u, 0x10000u}, kmx[2] = {0u, 0u};
  #pragma unroll
  for (int s = 0; s < 6; ++s) {
    #pragma unroll
    for (int r = 0; r < 2; ++r) {
      unsigned k = ck[r][s] >> 13;
      if (k <= 0xFFFFu) {
        kmn[r] = k < kmn[r] ? k : kmn[r];
        kmx[r] = k > kmx[r] ? k : kmx[r];
      }
    }
  }
  #pragma unroll
  for (int off = 32; off > 0; off >>= 1) {
    #pragma unroll
    for (int r = 0; r < 2; ++r) {
      unsigned o1 = __shfl_xor(kmn[r], off); kmn[r] = o1 < kmn[r] ? o1 : kmn[r];
      unsigned o2 = __shfl_xor(kmx[r], off); kmx[r] = o2 > kmx[r] ? o2 : kmx[r];
    }
  }

  // ---- dual bisection 2: T[r] = exact 32nd-smallest collected key ----
  #pragma unroll
  for (int r = 0; r < 2; ++r) { lo[r] = (long long)kmn[r] - 1; hi[r] = (long long)kmx[r]; }
  while ((hi[0] - lo[0] > 1) || (hi[1] - lo[1] > 1)) {
    unsigned mm[2][3];
    int cnt[2][3] = {};
    #pragma unroll
    for (int r = 0; r < 2; ++r) {
      long long span = hi[r] - lo[r];
      mm[r][0] = (unsigned)(lo[r] + (span >> 2));
      mm[r][1] = (unsigned)(lo[r] + (span >> 1));
      mm[r][2] = (unsigned)(hi[r] - (span >> 2));
    }
    #pragma unroll
    for (int s = 0; s < 6; ++s) {
      #pragma unroll
      for (int r = 0; r < 2; ++r) {
        unsigned k = ck[r][s] >> 13;
        cnt[r][0] += (k <= mm[r][0]);
        cnt[r][1] += (k <= mm[r][1]);
        cnt[r][2] += (k <= mm[r][2]);
      }
    }
    #pragma unroll
    for (int off = 32; off > 0; off >>= 1) {
      #pragma unroll
      for (int r = 0; r < 2; ++r) {
        cnt[r][0] += __shfl_xor(cnt[r][0], off);
        cnt[r][1] += __shfl_xor(cnt[r][1], off);
        cnt[r][2] += __shfl_xor(cnt[r][2], off);
      }
    }
    #pragma unroll
    for (int r = 0; r < 2; ++r) {
      if (hi[r] - lo[r] > 1) {
        if (cnt[r][0] >= KNN)      { hi[r] = mm[r][0]; }
        else if (cnt[r][1] >= KNN) { lo[r] = mm[r][0]; hi[r] = mm[r][1]; }
        else if (cnt[r][2] >= KNN) { lo[r] = mm[r][1]; hi[r] = mm[r][2]; }
        else                       { lo[r] = mm[r][2]; }
      }
    }
  }
  const unsigned T[2] = {(unsigned)hi[0], (unsigned)hi[1]};

  // ---- dual classify ----
  int sA[2] = {0, 0}, sB[2] = {0, 0};
  #pragma unroll
  for (int s = 0; s < 6; ++s) {
    #pragma unroll
    for (int r = 0; r < 2; ++r) {
      unsigned k = ck[r][s] >> 13;
      bool strict = (k < T[r]);
      u64 ms = __ballot(strict);
      if (strict) {
        int pos = sA[r] + (int)__popcll(ms & below);
        if (pos < 32) neighS[wv][r][pos] = (int)(ck[r][s] & 0x1FFFu);
      }
      sA[r] += (int)__popcll(ms);
      bool tie = (k == T[r]);
      u64 mt2 = __ballot(tie);
      if (tie) {
        int pos = sB[r] + (int)__popcll(mt2 & below);
        if (pos < 128) tieS[wv][r][pos] = (u16)(ck[r][s] & 0x1FFFu);
      }
      sB[r] += (int)__popcll(mt2);
    }
  }
  #pragma unroll
  for (int r = 0; r < 2; ++r) if (sB[r] > 128) sB[r] = 128;
  const int need[2] = {KNN - sA[0], KNN - sA[1]};
  const bool doref[2] = {sB[0] != need[0], sB[1] != need[1]};

  // ---- dual tie-refine dots (interleaved) ----
  u64 rk[2][2] = {{~0ull, ~0ull}, {~0ull, ~0ull}};
  #pragma unroll
  for (int half = 0; half < 2; ++half) {
    #pragma unroll
    for (int r = 0; r < 2; ++r) {
      int e = lane + half * 64;
      if (doref[r] && e < sB[r]) {
        int j = tieS[wv][r][e];
        const float* hi0 = &hiL[wv][r][0];
        const float* hj = hF + (size_t)j * H2_DIM;
        float d0 = 0.f, d1 = 0.f, d2 = 0.f, d3 = 0.f;
        for (int d = 0; d < H2_DIM; d += 16) {
          f32x4 a0 = *(const f32x4*)(hi0 + d);
          f32x4 b0 = *(const f32x4*)(hj + d);
          f32x4 a1 = *(const f32x4*)(hi0 + d + 4);
          f32x4 b1 = *(const f32x4*)(hj + d + 4);
          f32x4 a2 = *(const f32x4*)(hi0 + d + 8);
          f32x4 b2 = *(const f32x4*)(hj + d + 8);
          f32x4 a3 = *(const f32x4*)(hi0 + d + 12);
          f32x4 b3 = *(const f32x4*)(hj + d + 12);
          d0 = fmaf(a0[0], b0[0], fmaf(a0[1], b0[1], fmaf(a0[2], b0[2], fmaf(a0[3], b0[3], d0))));
          d1 = fmaf(a1[0], b1[0], fmaf(a1[1], b1[1], fmaf(a1[2], b1[2], fmaf(a1[3], b1[3], d1))));
          d2 = fmaf(a2[0], b2[0], fmaf(a2[1], b2[1], fmaf(a2[2], b2[2], fmaf(a2[3], b2[3], d2))));
          d3 = fmaf(a3[0], b3[0], fmaf(a3[1], b3[1], fmaf(a3[2], b3[2], fmaf(a3[3], b3[3], d3))));
        }
        float dot = (d0 + d1) + (d2 + d3);
        float f = fmaf(-2.f, dot, sq[j]);
        rk[r][half] = ((u64)sortkey(f) << 13) | (unsigned)j;
      }
    }
  }

  // ---- finalize each row (wave-uniform branches) ----
  #pragma unroll
  for (int r = 0; r < 2; ++r) {
    if (!doref[r]) {
      if (lane < need[r]) neighS[wv][r][sA[r] + lane] = tieS[wv][r][lane];
    } else {
      candS[wv][r][lane]       = (unsigned)(rk[r][0] >> 32);
      candS[wv][r][64 + lane]  = (unsigned)rk[r][0];
      candS[wv][r][128 + lane] = (unsigned)(rk[r][1] >> 32);
      candS[wv][r][192 + lane] = (unsigned)rk[r][1];
      u64 v0 = ((u64)candS[wv][r][(2 * lane) >= 64 ? 128 + (2 * lane - 64) : 2 * lane] << 32)
             | candS[wv][r][(2 * lane) >= 64 ? 192 + (2 * lane - 64) : 64 + 2 * lane];
      u64 v1 = ((u64)candS[wv][r][(2 * lane + 1) >= 64 ? 128 + (2 * lane + 1 - 64) : 2 * lane + 1] << 32)
             | candS[wv][r][(2 * lane + 1) >= 64 ? 192 + (2 * lane + 1 - 64) : 64 + 2 * lane + 1];
      const int e0 = 2 * lane, e1 = e0 + 1;
      for (int k = 2; k <= 128; k <<= 1) {
        for (int j = k >> 1; j >= 2; j >>= 1) {
          int half = j >> 1;
          u64 o0 = __shfl_xor(v0, half);
          u64 o1 = __shfl_xor(v1, half);
          bool up0 = ((e0 & k) == 0) == ((e0 & j) == 0);
          bool up1 = ((e1 & k) == 0) == ((e1 & j) == 0);
          v0 = up0 ? (v0 < o0 ? v0 : o0) : (v0 > o0 ? v0 : o0);
          v1 = up1 ? (v1 < o1 ? v1 : o1) : (v1 > o1 ? v1 : o1);
        }
        bool asc = ((e0 & k) == 0);
        u64 a = v0 < v1 ? v0 : v1, b = v0 < v1 ? v1 : v0;
        v0 = asc ? a : b;
        v1 = asc ? b : a;
      }
      if (e0 < need[r]) neighS[wv][r][sA[r] + e0] = (int)(v0 & 0x1FFFu);
      if (e1 < need[r]) neighS[wv][r][sA[r] + e1] = (int)(v1 & 0x1FFFu);
    }
    if (lane == 0) neighS[wv][r][32] = (r == 0) ? i0 : i1;
  }

  // ---- dual masked softmax ----
  float eA = -FLT_MAX, eB = -FLT_MAX;
  if (lane < 33) {
    float rawA = f1[i0] + f2[neighS[wv][0][lane]];
    float rawB = f1[i1] + f2[neighS[wv][1][lane]];
    eA = rawA > 0.f ? rawA : 0.2f * rawA;
    eB = rawB > 0.f ? rawB : 0.2f * rawB;
  }
  float mxA = eA, mxB = eB;
  #pragma unroll
  for (int off = 32; off > 0; off >>= 1) {
    mxA = fmaxf(mxA, __shfl_xor(mxA, off));
    mxB = fmaxf(mxB, __shfl_xor(mxB, off));
  }
  float exA = (lane < 33) ? expf(eA - mxA) : 0.f;
  float exB = (lane < 33) ? expf(eB - mxB) : 0.f;
  float smA = exA, smB = exB;
  #pragma unroll
  for (int off = 32; off > 0; off >>= 1) {
    smA += __shfl_xor(smA, off);
    smB += __shfl_xor(smB, off);
  }
  if (lane < 33) {
    attS[wv][0][lane] = exA / smA;
    attS[wv][1][lane] = exB / smB;
  }

  // ---- dual PV: lane = g ----
  {
    float s0 = 0.f, s1 = 0.f;
    for (int m = 0; m < 33; ++m) {
      s0 = fmaf(attS[wv][0][m], Wh[(size_t)neighS[wv][0][m] * G_DIM + lane], s0);
      s1 = fmaf(attS[wv][1][m], Wh[(size_t)neighS[wv][1][m] * G_DIM + lane], s1);
    }
    hpfS[wv][0][lane] = s0 > 0.f ? s0 : expm1f(s0);
    hpfS[wv][1][lane] = s1 > 0.f ? s1 : expm1f(s1);
  }

  // ---- dual head: 64 -> 22 ----
  if (lane < NOUT) {
    float o0 = bc[lane], o1 = bc[lane];
    for (int g = 0; g < 64; ++g) {
      float wgt = WcL[g * NOUT + lane];
      o0 = fmaf(hpfS[wv][0][g], wgt, o0);
      o1 = fmaf(hpfS[wv][1][g], wgt, o1);
    }
    out[(size_t)i0 * NOUT + lane] = o0;
    out[(size_t)i1 * NOUT + lane] = o1;
  }
}

extern "C" void kernel_launch(void* const* d_in, const int* in_sizes, int n_in,
                              void* d_out, int out_size, void* d_ws, size_t ws_size,
                              hipStream_t stream)
{
  const float* x  = (const float*)d_in[0];
  const float* W0 = (const float*)d_in[1];
  const float* b0 = (const float*)d_in[2];
  const float* W1 = (const float*)d_in[3];
  const float* b1 = (const float*)d_in[4];
  const float* gW = (const float*)d_in[5];
  const float* ga = (const float*)d_in[6];
  const float* cW = (const float*)d_in[7];
  const float* cb = (const float*)d_in[8];
  const float* dW = (const float*)d_in[9];
  const float* db = (const float*)d_in[10];
  float* out = (float*)d_out;

  char* base = (char*)d_ws;
  char* w = base;
  auto alloc = [&](size_t bytes) { char* p = w; w += (bytes + 255) & ~(size_t)255; return p; };
  u16 *W0p[3], *W1p[3], *gWp[3], *h1p[3], *hp[3];
  for (int p = 0; p < 3; ++p) W0p[p] = (u16*)alloc((size_t)D_IN * H1_DIM * 2);
  for (int p = 0; p < 3; ++p) W1p[p] = (u16*)alloc((size_t)H1_DIM * H2_DIM * 2);
  for (int p = 0; p < 3; ++p) gWp[p] = (u16*)alloc((size_t)H2_DIM * G_DIM * 2);
  for (int p = 0; p < 3; ++p) h1p[p] = (u16*)alloc((size_t)N_PTS * H1_DIM * 2);
  for (int p = 0; p < 3; ++p) hp[p]  = (u16*)alloc((size_t)N_PTS * H2_DIM * 2);
  float* hF  = (float*)alloc((size_t)N_PTS * H2_DIM * 4);
  float* WhF = (float*)alloc((size_t)N_PTS * G_DIM * 4);
  float* sqv = (float*)alloc(N_PTS * 4);
  float* f1v = (float*)alloc(N_PTS * 4);
  float* f2v = (float*)alloc(N_PTS * 4);
  float* Wc  = (float*)alloc(64 * NOUT * 4);
  float* bc  = (float*)alloc(64 * 4);
  u16* Qm    = (u16*)alloc((size_t)N_PTS * NQ * 2);

  char* pbase = w;
  const size_t MN1 = (size_t)N_PTS * H1_DIM;
  const size_t MN2 = (size_t)N_PTS * H2_DIM;
  const size_t MN3 = (size_t)N_PTS * G_DIM;
  float* P1 = (float*)alloc(4 * MN1 * 4);
  float* P2 = (float*)alloc(4 * MN2 * 4);
  float* P3 = (float*)alloc(4 * MN3 * 4);
  u16* Sb = (u16*)pbase;

  const int TS = D_IN * H1_DIM + H1_DIM * H2_DIM + H2_DIM * G_DIM + 64 * NOUT;
  prep_all<<<(TS + 255) / 256, 256, 0, stream>>>(
      W0, W0p[0], W0p[1], W0p[2], W1, W1p[0], W1p[1], W1p[2], gW, gWp[0], gWp[1], gWp[2],
      cW, cb, dW, db, Wc, bc);

  mfma_gemm<64, true, true, false, false, false, false>
      <<<dim3(H1_DIM / 64, N_PTS / 64, 4), 256, 0, stream>>>(
      x, nullptr, nullptr, W0p[0], W0p[1], W0p[2], nullptr,
      P1, nullptr, nullptr, nullptr, D_IN, D_IN / 4, H1_DIM, MN1);
  combine<4, true, true, false, true><<<(int)(MN1 / 1024), 256, 0, stream>>>(
      P1, b0, MN1, H1_DIM, nullptr, h1p[0], h1p[1], h1p[2]);

  mfma_gemm<64, false, true, false, false, false, false>
      <<<dim3(H2_DIM / 64, N_PTS / 64, 4), 256, 0, stream>>>(
      h1p[0], h1p[1], h1p[2], W1p[0], W1p[1], W1p[2], nullptr,
      P2, nullptr, nullptr, nullptr, H1_DIM, H1_DIM / 4, H2_DIM, MN2);
  combine<4, true, true, true, true><<<(int)(MN2 / 1024), 256, 0, stream>>>(
      P2, b1, MN2, H2_DIM, hF, hp[0], hp[1], hp[2]);

  mfma_gemm<64, false, true, false, false, false, false>
      <<<dim3(G_DIM / 64, N_PTS / 64, 4), 256, 0, stream>>>(
      hp[0], hp[1], hp[2], gWp[0], gWp[1], gWp[2], nullptr,
      P3, nullptr, nullptr, nullptr, H2_DIM, H2_DIM / 4, G_DIM, MN3);
  combine<4, false, false, true, false><<<(int)(MN3 / 1024), 256, 0, stream>>>(
      P3, nullptr, MN3, G_DIM, WhF, nullptr, nullptr, nullptr);

  row_stats<<<N_PTS / 256, 256, 0, stream>>>(hF, WhF, ga, sqv, f1v, f2v);

  gram_symm<<<dim3(N_PTS / 128, N_PTS / 128), 512, 0, stream>>>(
      hp[0], hp[1], hp[2], sqv, Sb, Qm, N_PTS);
  topk_att<<<N_PTS / 8, 256, 0, stream>>>(Sb, Qm, f1v, f2v, WhF, Wc, bc, sqv, hF, out, 0, N_PTS);
}

// Round 25
// 153.032 us; speedup vs baseline: 1.0649x; 1.0649x over previous
//
#include <hip/hip_runtime.h>
#include <float.h>

#define N_PTS 6144
#define D_IN  512
#define H1_DIM 256
#define H2_DIM 128
#define G_DIM  64
#define KNN    32
#define NOUT   22

typedef short s8v __attribute__((ext_vector_type(8)));   // 8 bf16 in 4 VGPR
typedef float f32x4 __attribute__((ext_vector_type(4)));
typedef unsigned u32x4 __attribute__((ext_vector_type(4)));
typedef unsigned short u16;
typedef unsigned short u16x4 __attribute__((ext_vector_type(4)));
typedef unsigned long long u64;

__device__ __forceinline__ u16 f2bf(float f) {
  unsigned u = __float_as_uint(f);
  u += 0x7FFFu + ((u >> 16) & 1u);          // RNE to bf16
  return (u16)(u >> 16);
}
__device__ __forceinline__ float bf2f(u16 s) {
  return __uint_as_float(((unsigned)s) << 16);
}
__device__ __forceinline__ void split3(float v, u16& a0, u16& a1, u16& a2) {
  a0 = f2bf(v);
  float r1 = v - bf2f(a0);
  a1 = f2bf(r1);
  a2 = f2bf(r1 - bf2f(a1));
}
__device__ __forceinline__ unsigned sortkey(float f) {
  unsigned ub = __float_as_uint(f);
  return (ub & 0x80000000u) ? ~ub : (ub | 0x80000000u);
}

// ---------------------------------------------------------------------------
// Generic MFMA GEMM (MLP path), 3-way bf16 split, 6-term schedule.
// ---------------------------------------------------------------------------
template<int BM, bool AF32, bool SPLITK, bool BIAS, bool RELU, bool WF32, bool WSPLIT>
__global__ __launch_bounds__(256, 4) void mfma_gemm(
    const void* __restrict__ A0any, const u16* __restrict__ A1_, const u16* __restrict__ A2_,
    const u16* __restrict__ B0_, const u16* __restrict__ B1_, const u16* __restrict__ B2_,
    const float* __restrict__ bias,
    float* __restrict__ Cf, u16* __restrict__ C0, u16* __restrict__ C1, u16* __restrict__ C2,
    int Ktot, int Ks, int ldC, size_t MN)
{
  const int MT = BM / 32, NT = 2;
  const int APL = BM * 32;
  const int BBASE = 3 * APL;
  __shared__ u16 lds[(BM + 64) * 32 * 3];

  const int t = threadIdx.x;
  const int lane = t & 63, wave = t >> 6;
  const int wm = wave >> 1, wn = wave & 1;
  const int m0 = blockIdx.y * BM, n0 = blockIdx.x * 64;
  const int kz = blockIdx.z * Ks;

  f32x4 acc[MT][NT] = {};

  const int pA = BM / 16;
  const int NC = 3 * pA + 12;

  for (int k0 = 0; k0 < Ks; k0 += 32) {
    if (k0) __syncthreads();
    const int kb = kz + k0;
    if (AF32) {
      const float* A = (const float*)A0any;
      #pragma unroll
      for (int c0 = 0; c0 < BM * 4; c0 += 256) {
        int c = c0 + t;
        int row = c >> 2, slot = c & 3;
        const float* g = A + (size_t)(m0 + row) * Ktot + kb + slot * 8;
        f32x4 fa = *(const f32x4*)g;
        f32x4 fb = *(const f32x4*)(g + 4);
        int dst = row * 32 + ((slot ^ ((row >> 1) & 3)) << 3);
        s8v v0, v1, v2;
        #pragma unroll
        for (int e = 0; e < 4; ++e) {
          u16 a0, a1, a2; split3(fa[e], a0, a1, a2);
          v0[e] = (short)a0; v1[e] = (short)a1; v2[e] = (short)a2;
        }
        #pragma unroll
        for (int e = 0; e < 4; ++e) {
          u16 a0, a1, a2; split3(fb[e], a0, a1, a2);
          v0[4 + e] = (short)a0; v1[4 + e] = (short)a1; v2[4 + e] = (short)a2;
        }
        *(s8v*)(lds + dst) = v0;
        *(s8v*)(lds + APL + dst) = v1;
        *(s8v*)(lds + 2 * APL + dst) = v2;
      }
      for (int c = wave; c < 12; c += 4) {
        int p = c >> 2, lc = c & 3;
        int row = lc * 16 + (lane >> 2);
        int srcslot = (lane & 3) ^ ((row >> 1) & 3);
        const u16* src = (p == 0) ? B0_ : (p == 1) ? B1_ : B2_;
        const u16* g = src + (size_t)(n0 + row) * Ktot + kb + srcslot * 8;
        __builtin_amdgcn_global_load_lds(
            (const __attribute__((address_space(1))) unsigned*)g,
            (__attribute__((address_space(3))) unsigned*)(lds + BBASE + p * 2048 + lc * 512),
            16, 0, 0);
      }
    } else {
      for (int c = wave; c < NC; c += 4) {
        const u16* src; int dstoff; int row0; int lc;
        if (c < 3 * pA) {
          int p = c / pA; lc = c % pA;
          src = (p == 0) ? (const u16*)A0any : (p == 1) ? A1_ : A2_;
          dstoff = p * APL + lc * 512;
          row0 = m0;
        } else {
          int cb = c - 3 * pA;
          int p = cb >> 2; lc = cb & 3;
          src = (p == 0) ? B0_ : (p == 1) ? B1_ : B2_;
          dstoff = BBASE + p * 2048 + lc * 512;
          row0 = n0;
        }
        int row = lc * 16 + (lane >> 2);
        int srcslot = (lane & 3) ^ ((row >> 1) & 3);
        const u16* g = src + (size_t)(row0 + row) * Ktot + kb + srcslot * 8;
        __builtin_amdgcn_global_load_lds(
            (const __attribute__((address_space(1))) unsigned*)g,
            (__attribute__((address_space(3))) unsigned*)(lds + dstoff),
            16, 0, 0);
      }
    }
    __syncthreads();

    s8v af[3][MT], bf[3][NT];
    #pragma unroll
    for (int mt = 0; mt < MT; ++mt) {
      int r = wm * (BM / 2) + mt * 16 + (lane & 15);
      int off = r * 32 + (((lane >> 4) ^ ((r >> 1) & 3)) << 3);
      #pragma unroll
      for (int p = 0; p < 3; ++p) af[p][mt] = *(const s8v*)(lds + p * APL + off);
    }
    #pragma unroll
    for (int nt = 0; nt < NT; ++nt) {
      int r = wn * 32 + nt * 16 + (lane & 15);
      int off = r * 32 + (((lane >> 4) ^ ((r >> 1) & 3)) << 3);
      #pragma unroll
      for (int p = 0; p < 3; ++p) bf[p][nt] = *(const s8v*)(lds + BBASE + p * 2048 + off);
    }
    #pragma unroll
    for (int mt = 0; mt < MT; ++mt)
      #pragma unroll
      for (int nt = 0; nt < NT; ++nt) {
        f32x4 a = acc[mt][nt];
        a = __builtin_amdgcn_mfma_f32_16x16x32_bf16(af[0][mt], bf[0][nt], a, 0, 0, 0);
        a = __builtin_amdgcn_mfma_f32_16x16x32_bf16(af[0][mt], bf[1][nt], a, 0, 0, 0);
        a = __builtin_amdgcn_mfma_f32_16x16x32_bf16(af[1][mt], bf[0][nt], a, 0, 0, 0);
        a = __builtin_amdgcn_mfma_f32_16x16x32_bf16(af[1][mt], bf[1][nt], a, 0, 0, 0);
        a = __builtin_amdgcn_mfma_f32_16x16x32_bf16(af[0][mt], bf[2][nt], a, 0, 0, 0);
        a = __builtin_amdgcn_mfma_f32_16x16x32_bf16(af[2][mt], bf[0][nt], a, 0, 0, 0);
        acc[mt][nt] = a;
      }
  }

  #pragma unroll
  for (int mt = 0; mt < MT; ++mt) {
    #pragma unroll
    for (int nt = 0; nt < NT; ++nt) {
      int col = n0 + wn * 32 + nt * 16 + (lane & 15);
      float bv = (BIAS && !SPLITK) ? bias[col] : 0.f;
      #pragma unroll
      for (int v = 0; v < 4; ++v) {
        int row = m0 + wm * (BM / 2) + mt * 16 + (lane >> 4) * 4 + v;
        float val = acc[mt][nt][v] + bv;
        size_t o = (size_t)row * ldC + col;
        if (SPLITK) {
          Cf[(size_t)blockIdx.z * MN + o] = val;
        } else {
          if (RELU) val = fmaxf(val, 0.f);
          if (WF32) Cf[o] = val;
          if (WSPLIT) {
            u16 a0, a1, a2; split3(val, a0, a1, a2);
            C0[o] = a0; C1[o] = a1; C2[o] = a2;
          }
        }
      }
    }
  }
}

// ---------------------------------------------------------------------------
// Symmetric Gram, 128x128 tile, 512 threads (8 waves, 2x4). u16-key epilogue;
// upper-triangle blocks only (x>=y); x>y also writes mirrored keys transposed
// through LDS. LDS 48KB.
// ---------------------------------------------------------------------------
__global__ __launch_bounds__(512, 4) void gram_symm(
    const u16* __restrict__ A0, const u16* __restrict__ A1, const u16* __restrict__ A2,
    const float* __restrict__ sq, u16* __restrict__ Ck, int ldC)
{
  if ((int)blockIdx.x < (int)blockIdx.y) return;
  const int MT = 4, NT = 2;
  __shared__ u16 lds[2 * 128 * 32 * 3];          // 48 KB

  const int t = threadIdx.x;
  const int lane = t & 63, wave = t >> 6;        // wave 0..7
  const int wm = wave >> 2, wn = wave & 3;       // 2 x 4 wave grid
  const int m0 = blockIdx.y * 128, n0 = blockIdx.x * 128;
  const bool mirror = (int)blockIdx.x > (int)blockIdx.y;

  f32x4 acc[MT][NT] = {};

  for (int k0 = 0; k0 < H2_DIM; k0 += 32) {
    if (k0) __syncthreads();
    for (int c = wave; c < 48; c += 8) {
      int half = c >= 24;                        // 0 = A rows, 1 = B rows
      int cb = half ? c - 24 : c;
      int p = cb >> 3, lc = cb & 7;
      const u16* src = (p == 0) ? A0 : (p == 1) ? A1 : A2;
      int dstoff = half * 12288 + p * 4096 + lc * 512;
      int row0 = half ? n0 : m0;
      int row = lc * 16 + (lane >> 2);
      int srcslot = (lane & 3) ^ ((row >> 1) & 3);
      const u16* g = src + (size_t)(row0 + row) * H2_DIM + k0 + srcslot * 8;
      __builtin_amdgcn_global_load_lds(
          (const __attribute__((address_space(1))) unsigned*)g,
          (__attribute__((address_space(3))) unsigned*)(lds + dstoff),
          16, 0, 0);
    }
    __syncthreads();

    s8v af[3][MT], bf[3][NT];
    #pragma unroll
    for (int mt = 0; mt < MT; ++mt) {
      int r = wm * 64 + mt * 16 + (lane & 15);
      int off = r * 32 + (((lane >> 4) ^ ((r >> 1) & 3)) << 3);
      #pragma unroll
      for (int p = 0; p < 3; ++p) af[p][mt] = *(const s8v*)(lds + p * 4096 + off);
    }
    #pragma unroll
    for (int nt = 0; nt < NT; ++nt) {
      int r = wn * 32 + nt * 16 + (lane & 15);
      int off = r * 32 + (((lane >> 4) ^ ((r >> 1) & 3)) << 3);
      #pragma unroll
      for (int p = 0; p < 3; ++p) bf[p][nt] = *(const s8v*)(lds + 12288 + p * 4096 + off);
    }
    #pragma unroll
    for (int mt = 0; mt < MT; ++mt)
      #pragma unroll
      for (int nt = 0; nt < NT; ++nt) {
        f32x4 a = acc[mt][nt];
        a = __builtin_amdgcn_mfma_f32_16x16x32_bf16(af[0][mt], bf[0][nt], a, 0, 0, 0);
        a = __builtin_amdgcn_mfma_f32_16x16x32_bf16(af[0][mt], bf[1][nt], a, 0, 0, 0);
        a = __builtin_amdgcn_mfma_f32_16x16x32_bf16(af[1][mt], bf[0][nt], a, 0, 0, 0);
        a = __builtin_amdgcn_mfma_f32_16x16x32_bf16(af[1][mt], bf[1][nt], a, 0, 0, 0);
        a = __builtin_amdgcn_mfma_f32_16x16x32_bf16(af[0][mt], bf[2][nt], a, 0, 0, 0);
        a = __builtin_amdgcn_mfma_f32_16x16x32_bf16(af[2][mt], bf[0][nt], a, 0, 0, 0);
        acc[mt][nt] = a;
      }
  }

  // epilogue: direct keys into lds as [128][136], mirror keys packed in regs
  unsigned mk32[MT][NT][2];
  __syncthreads();
  u16* stD = lds;
  #pragma unroll
  for (int mt = 0; mt < MT; ++mt) {
    #pragma unroll
    for (int nt = 0; nt < NT; ++nt) {
      int cl = wn * 32 + nt * 16 + (lane & 15);
      float sqc = sq[n0 + cl];
      #pragma unroll
      for (int v = 0; v < 4; ++v) {
        int rl = wm * 64 + mt * 16 + (lane >> 4) * 4 + v;
        float val = acc[mt][nt][v];
        float f = fmaf(-2.f, val, sqc);
        unsigned uu = sortkey(f);
        if (m0 + rl == n0 + cl) uu = 0xFFFFFFFFu;
        stD[rl * 136 + cl] = (u16)(uu >> 16);
        if (mirror) {
          unsigned km = sortkey(fmaf(-2.f, val, sq[m0 + rl])) >> 16;
          if (v & 1) mk32[mt][nt][v >> 1] |= km << 16;
          else       mk32[mt][nt][v >> 1] = km;
        }
      }
    }
  }
  __syncthreads();
  for (int e = t; e < 128 * 16; e += 512) {
    int row = e >> 4, ch = e & 15;
    u32x4 vv = *(const u32x4*)(stD + row * 136 + ch * 8);
    *(u32x4*)(Ck + (size_t)(m0 + row) * ldC + n0 + ch * 8) = vv;
  }
  if (mirror) {
    __syncthreads();
    u16* stM = lds;
    #pragma unroll
    for (int mt = 0; mt < MT; ++mt) {
      #pragma unroll
      for (int nt = 0; nt < NT; ++nt) {
        int cl = wn * 32 + nt * 16 + (lane & 15);
        #pragma unroll
        for (int v = 0; v < 4; ++v) {
          int rl = wm * 64 + mt * 16 + (lane >> 4) * 4 + v;
          unsigned km = (v & 1) ? (mk32[mt][nt][v >> 1] >> 16)
                                : (mk32[mt][nt][v >> 1] & 0xFFFFu);
          stM[cl * 136 + rl] = (u16)km;
        }
      }
    }
    __syncthreads();
    for (int e = t; e < 128 * 16; e += 512) {
      int row = e >> 4, ch = e & 15;
      u32x4 vv = *(const u32x4*)(stM + row * 136 + ch * 8);
      *(u32x4*)(Ck + (size_t)(n0 + row) * ldC + m0 + ch * 8) = vv;
    }
  }
}

// generic combine (gemm1): bias+relu -> 3-plane split
template<int S>
__global__ void combine_s(const float* __restrict__ P, const float* __restrict__ bias,
                          size_t MN, int Ncols,
                          u16* __restrict__ C0, u16* __restrict__ C1, u16* __restrict__ C2)
{
  size_t idx = ((size_t)blockIdx.x * 256 + threadIdx.x) * 4;
  if (idx >= MN) return;
  f32x4 s = *(const f32x4*)(P + idx);
  #pragma unroll
  for (int z = 1; z < S; ++z) s += *(const f32x4*)(P + (size_t)z * MN + idx);
  int n = (int)(idx % (size_t)Ncols);
  #pragma unroll
  for (int e = 0; e < 4; ++e) {
    float v = s[e] + bias[n + e];
    v = fmaxf(v, 0.f);
    u16 a0, a1, a2; split3(v, a0, a1, a2);
    C0[idx + e] = a0; C1[idx + e] = a1; C2[idx + e] = a2;
  }
}

// combine for gemm2 (h): bias+relu -> hF fp32 + 3-plane split + fused sq[row]
// (block = 1024 elems = 8 rows of 128; each 32-lane group covers one row)
__global__ void combine_h(const float* __restrict__ P, const float* __restrict__ bias,
                          size_t MN,
                          float* __restrict__ hF, u16* __restrict__ C0,
                          u16* __restrict__ C1, u16* __restrict__ C2,
                          float* __restrict__ sq)
{
  const int t = threadIdx.x;
  size_t idx = ((size_t)blockIdx.x * 256 + t) * 4;
  f32x4 s = *(const f32x4*)(P + idx);
  #pragma unroll
  for (int z = 1; z < 4; ++z) s += *(const f32x4*)(P + (size_t)z * MN + idx);
  int n = (int)(idx % (size_t)H2_DIM);
  float ss = 0.f;
  #pragma unroll
  for (int e = 0; e < 4; ++e) {
    float v = s[e] + bias[n + e];
    v = fmaxf(v, 0.f);
    hF[idx + e] = v;
    u16 a0, a1, a2; split3(v, a0, a1, a2);
    C0[idx + e] = a0; C1[idx + e] = a1; C2[idx + e] = a2;
    ss = fmaf(v, v, ss);
  }
  #pragma unroll
  for (int off = 1; off <= 16; off <<= 1) ss += __shfl_xor(ss, off);
  if ((t & 31) == 0) sq[blockIdx.x * 8 + (t >> 5)] = ss;
}

// combine for gemm3 (Wh): -> WhF fp32 + fused f1/f2 (dot with ga halves)
// (block = 1024 elems = 16 rows of 64; each 16-lane group covers one row)
__global__ void combine_wh(const float* __restrict__ P, size_t MN,
                           float* __restrict__ WhF, const float* __restrict__ ga,
                           float* __restrict__ f1, float* __restrict__ f2)
{
  const int t = threadIdx.x;
  size_t idx = ((size_t)blockIdx.x * 256 + t) * 4;
  f32x4 s = *(const f32x4*)(P + idx);
  #pragma unroll
  for (int z = 1; z < 4; ++z) s += *(const f32x4*)(P + (size_t)z * MN + idx);
  int c0 = (int)(idx % (size_t)G_DIM);
  float a = 0.f, b = 0.f;
  #pragma unroll
  for (int e = 0; e < 4; ++e) {
    float v = s[e];
    WhF[idx + e] = v;
    a = fmaf(v, ga[c0 + e], a);
    b = fmaf(v, ga[G_DIM + c0 + e], b);
  }
  #pragma unroll
  for (int off = 1; off <= 8; off <<= 1) {
    a += __shfl_xor(a, off);
    b += __shfl_xor(b, off);
  }
  if ((t & 15) == 0) {
    int row = blockIdx.x * 16 + (t >> 4);
    f1[row] = a; f2[row] = b;
  }
}

// weight transposes+splits AND head collapse in one launch
__global__ void prep_all(const float* __restrict__ W0, u16* __restrict__ a0,
                         u16* __restrict__ a1, u16* __restrict__ a2,
                         const float* __restrict__ W1, u16* __restrict__ b0,
                         u16* __restrict__ b1, u16* __restrict__ b2,
                         const float* __restrict__ gW, u16* __restrict__ c0,
                         u16* __restrict__ c1, u16* __restrict__ c2,
                         const float* __restrict__ cW, const float* __restrict__ cb,
                         const float* __restrict__ dW, const float* __restrict__ db,
                         float* __restrict__ Wc, float* __restrict__ bc)
{
  int id = blockIdx.x * 256 + threadIdx.x;
  const int S0 = D_IN * H1_DIM, S1 = H1_DIM * H2_DIM, S2 = H2_DIM * G_DIM;
  const int SW = S0 + S1 + S2;
  if (id < SW) {
    const float* W; u16 *p0, *p1, *p2; int K, N;
    if (id < S0)           { W = W0; p0 = a0; p1 = a1; p2 = a2; K = D_IN;   N = H1_DIM; }
    else if (id < S0 + S1) { id -= S0; W = W1; p0 = b0; p1 = b1; p2 = b2; K = H1_DIM; N = H2_DIM; }
    else                   { id -= S0 + S1; W = gW; p0 = c0; p1 = c1; p2 = c2; K = H2_DIM; N = G_DIM; }
    int k = id / N, n = id % N;
    u16 x0, x1, x2;
    split3(W[id], x0, x1, x2);
    size_t o = (size_t)n * K + k;
    p0[o] = x0; p1[o] = x1; p2[o] = x2;
    return;
  }
  id -= SW;
  if (id < 64 * NOUT) {
    int g = id / NOUT, c = id % NOUT;
    float s = 0.f;
    if (c < 16) {
      for (int r = 0; r < 8; ++r) s += cW[(r * 64 + g) * 16 + c];
    } else {
      int k = (c - 16) >> 1, o = (c - 16) & 1;
      for (int r = 0; r < 8; ++r) s += dW[k * 1024 + (r * 64 + g) * 2 + o];
    }
    Wc[id] = s;
    if (g == 0) bc[c] = (c < 16) ? cb[c] : db[c - 16];
  }
}

// ---------------------------------------------------------------------------
// u16-key topk (r21-proven), one wave per row, reversed row order.
// ---------------------------------------------------------------------------
__global__ __launch_bounds__(256) void topk_att(const u16* __restrict__ Sb,
    const float* __restrict__ f1, const float* __restrict__ f2,
    const float* __restrict__ Wh, const float* __restrict__ Wc, const float* __restrict__ bc,
    const float* __restrict__ sq, const float* __restrict__ hF,
    float* __restrict__ out, int m0, int nrows)
{
  const int t = threadIdx.x;
  const int lane = t & 63, wv = t >> 6;
  const int row4 = (nrows - 4 - blockIdx.x * 4) + wv;   // reversed mapping
  const int i = m0 + row4;
  const u16* Srow = Sb + (size_t)row4 * N_PTS;

  __shared__ float WcL[64 * NOUT];
  __shared__ unsigned candS[4][384];
  __shared__ u16 tieS[4][128];
  __shared__ float hiL[4][128];
  __shared__ int neighS[4][33];
  __shared__ float attS[4][33];
  __shared__ float hpfS[4][64];

  for (int idx = t; idx < 64 * NOUT; idx += 256) WcL[idx] = Wc[idx];
  __syncthreads();                       // only block barrier

  hiL[wv][lane]      = hF[(size_t)i * H2_DIM + lane];
  hiL[wv][64 + lane] = hF[(size_t)i * H2_DIM + 64 + lane];

  unsigned q[24];
  #pragma unroll
  for (int c = 0; c < 24; ++c) {
    u16x4 v = *(const u16x4*)(Srow + (c << 8) + (lane << 2));
    unsigned a = v[0] < v[1] ? (unsigned)v[0] : (unsigned)v[1];
    unsigned b = v[2] < v[3] ? (unsigned)v[2] : (unsigned)v[3];
    q[c] = a < b ? a : b;
  }

  unsigned lmin = q[0];
  #pragma unroll
  for (int c = 1; c < 24; ++c) lmin = q[c] < lmin ? q[c] : lmin;

  unsigned mnl = lmin, mxl = lmin;
  #pragma unroll
  for (int off = 32; off > 0; off >>= 1) {
    unsigned o1 = __shfl_xor(mnl, off); mnl = o1 < mnl ? o1 : mnl;
    unsigned o2 = __shfl_xor(mxl, off); mxl = o2 > mxl ? o2 : mxl;
  }

  long long lo = (long long)mnl - 1, hi = (long long)mxl;
  while (hi - lo > 1) {
    long long span = hi - lo;
    unsigned m1 = (unsigned)(lo + (span >> 2));
    unsigned m2 = (unsigned)(lo + (span >> 1));
    unsigned m3 = (unsigned)(hi - (span >> 2));
    int c1 = 0, c2 = 0, c3 = 0;
    #pragma unroll
    for (int c = 0; c < 24; ++c) {
      c1 += (q[c] <= m1);
      c2 += (q[c] <= m2);
      c3 += (q[c] <= m3);
    }
    #pragma unroll
    for (int off = 32; off > 0; off >>= 1) {
      c1 += __shfl_xor(c1, off);
      c2 += __shfl_xor(c2, off);
      c3 += __shfl_xor(c3, off);
    }
    if (c1 >= KNN)       { hi = m1; }
    else if (c2 >= KNN)  { lo = m1; hi = m2; }
    else if (c3 >= KNN)  { lo = m2; hi = m3; }
    else                 { lo = m3; }
  }
  const unsigned Q = (unsigned)hi;

  #pragma unroll
  for (int s = 0; s < 6; ++s) candS[wv][lane + s * 64] = 0xFFFFFFFFu;
  const u64 below = (lane == 0) ? 0ull : (~0ull >> (64 - lane));
  int qcnt = 0;
  #pragma unroll
  for (int c = 0; c < 24; ++c) {
    bool act = (q[c] <= Q);
    u64 mask = __ballot(act);
    if (act) {
      int pos = qcnt + (int)__popcll(mask & below);
      if (pos < 96) {
        u16x4 v = *(const u16x4*)(Srow + (c << 8) + (lane << 2));
        #pragma unroll
        for (int e = 0; e < 4; ++e) {
          int j = (c << 8) + (lane << 2) + e;
          candS[wv][pos * 4 + e] = ((unsigned)v[e] << 13) | (unsigned)j;
        }
      }
    }
    qcnt += (int)__popcll(mask);
  }

  unsigned ck[6];
  #pragma unroll
  for (int s = 0; s < 6; ++s) ck[s] = candS[wv][lane + s * 64];

  lo = -1; hi = 0x10000;
  while (hi - lo > 1) {
    long long span = hi - lo;
    unsigned m1 = (unsigned)(lo + (span >> 2));
    unsigned m2 = (unsigned)(lo + (span >> 1));
    unsigned m3 = (unsigned)(hi - (span >> 2));
    int c1 = 0, c2 = 0, c3 = 0;
    #pragma unroll
    for (int s = 0; s < 6; ++s) {
      unsigned k = ck[s] >> 13;
      c1 += (k <= m1);
      c2 += (k <= m2);
      c3 += (k <= m3);
    }
    #pragma unroll
    for (int off = 32; off > 0; off >>= 1) {
      c1 += __shfl_xor(c1, off);
      c2 += __shfl_xor(c2, off);
      c3 += __shfl_xor(c3, off);
    }
    if (c1 >= KNN)       { hi = m1; }
    else if (c2 >= KNN)  { lo = m1; hi = m2; }
    else if (c3 >= KNN)  { lo = m2; hi = m3; }
    else                 { lo = m3; }
  }
  const unsigned T = (unsigned)hi;

  int sA = 0, sB = 0;
  #pragma unroll
  for (int s = 0; s < 6; ++s) {
    unsigned k = ck[s] >> 13;
    bool strict = (k < T);
    u64 ms = __ballot(strict);
    if (strict) {
      int pos = sA + (int)__popcll(ms & below);
      if (pos < 32) neighS[wv][pos] = (int)(ck[s] & 0x1FFFu);
    }
    sA += (int)__popcll(ms);
    bool tie = (k == T);
    u64 mt2 = __ballot(tie);
    if (tie) {
      int pos = sB + (int)__popcll(mt2 & below);
      if (pos < 128) tieS[wv][pos] = (u16)(ck[s] & 0x1FFFu);
    }
    sB += (int)__popcll(mt2);
  }
  if (sB > 128) sB = 128;
  const int need = KNN - sA;

  u64 r0 = ~0ull, r1 = ~0ull;
  const float* hi0 = &hiL[wv][0];
  #pragma unroll
  for (int half = 0; half < 2; ++half) {
    int e = lane + half * 64;
    if (e < sB) {
      int j = tieS[wv][e];
      const float* hj = hF + (size_t)j * H2_DIM;
      float dot = 0.f;
      for (int d = 0; d < H2_DIM; d += 4) {
        f32x4 a = *(const f32x4*)(hi0 + d);
        f32x4 b = *(const f32x4*)(hj + d);
        dot = fmaf(a[0], b[0], fmaf(a[1], b[1], fmaf(a[2], b[2], fmaf(a[3], b[3], dot))));
      }
      float f = fmaf(-2.f, dot, sq[j]);
      u64 rk = ((u64)sortkey(f) << 13) | (unsigned)j;
      if (half == 0) r0 = rk; else r1 = rk;
    }
  }

  {
    candS[wv][lane] = (unsigned)(r0 >> 32); candS[wv][64 + lane] = (unsigned)r0;
    candS[wv][128 + lane] = (unsigned)(r1 >> 32); candS[wv][192 + lane] = (unsigned)r1;
    u64 v0 = ((u64)candS[wv][(2 * lane) >= 64 ? 128 + (2 * lane - 64) : 2 * lane] << 32)
           | candS[wv][(2 * lane) >= 64 ? 192 + (2 * lane - 64) : 64 + 2 * lane];
    u64 v1 = ((u64)candS[wv][(2 * lane + 1) >= 64 ? 128 + (2 * lane + 1 - 64) : 2 * lane + 1] << 32)
           | candS[wv][(2 * lane + 1) >= 64 ? 192 + (2 * lane + 1 - 64) : 64 + 2 * lane + 1];
    const int e0 = 2 * lane, e1 = e0 + 1;
    for (int k = 2; k <= 128; k <<= 1) {
      for (int j = k >> 1; j >= 2; j >>= 1) {
        int half = j >> 1;
        u64 o0 = __shfl_xor(v0, half);
        u64 o1 = __shfl_xor(v1, half);
        bool up0 = ((e0 & k) == 0) == ((e0 & j) == 0);
        bool up1 = ((e1 & k) == 0) == ((e1 & j) == 0);
        v0 = up0 ? (v0 < o0 ? v0 : o0) : (v0 > o0 ? v0 : o0);
        v1 = up1 ? (v1 < o1 ? v1 : o1) : (v1 > o1 ? v1 : o1);
      }
      bool asc = ((e0 & k) == 0);
      u64 a = v0 < v1 ? v0 : v1, b = v0 < v1 ? v1 : v0;
      v0 = asc ? a : b;
      v1 = asc ? b : a;
    }
    if (e0 < need) neighS[wv][sA + e0] = (int)(v0 & 0x1FFFu);
    if (e1 < need) neighS[wv][sA + e1] = (int)(v1 & 0x1FFFu);
  }
  if (lane == 0) neighS[wv][32] = i;

  {
    float e = -FLT_MAX;
    if (lane < 33) {
      float raw = f1[i] + f2[neighS[wv][lane]];
      e = raw > 0.f ? raw : 0.2f * raw;
    }
    float mx = e;
    #pragma unroll
    for (int off = 32; off > 0; off >>= 1) mx = fmaxf(mx, __shfl_xor(mx, off));
    float ex = (lane < 33) ? expf(e - mx) : 0.f;
    float sm = ex;
    #pragma unroll
    for (int off = 32; off > 0; off >>= 1) sm += __shfl_xor(sm, off);
    if (lane < 33) attS[wv][lane] = ex / sm;
  }

  {
    float s = 0.f;
    for (int m = 0; m < 33; ++m)
      s = fmaf(attS[wv][m], Wh[(size_t)neighS[wv][m] * G_DIM + lane], s);
    hpfS[wv][lane] = s > 0.f ? s : expm1f(s);
  }

  if (lane < NOUT) {
    float o = bc[lane];
    for (int g = 0; g < 64; ++g) o = fmaf(hpfS[wv][g], WcL[g * NOUT + lane], o);
    out[(size_t)i * NOUT + lane] = o;
  }
}

extern "C" void kernel_launch(void* const* d_in, const int* in_sizes, int n_in,
                              void* d_out, int out_size, void* d_ws, size_t ws_size,
                              hipStream_t stream)
{
  const float* x  = (const float*)d_in[0];
  const float* W0 = (const float*)d_in[1];
  const float* b0 = (const float*)d_in[2];
  const float* W1 = (const float*)d_in[3];
  const float* b1 = (const float*)d_in[4];
  const float* gW = (const float*)d_in[5];
  const float* ga = (const float*)d_in[6];
  const float* cW = (const float*)d_in[7];
  const float* cb = (const float*)d_in[8];
  const float* dW = (const float*)d_in[9];
  const float* db = (const float*)d_in[10];
  float* out = (float*)d_out;

  char* base = (char*)d_ws;
  char* w = base;
  auto alloc = [&](size_t bytes) { char* p = w; w += (bytes + 255) & ~(size_t)255; return p; };
  u16 *W0p[3], *W1p[3], *gWp[3], *h1p[3], *hp[3];
  for (int p = 0; p < 3; ++p) W0p[p] = (u16*)alloc((size_t)D_IN * H1_DIM * 2);
  for (int p = 0; p < 3; ++p) W1p[p] = (u16*)alloc((size_t)H1_DIM * H2_DIM * 2);
  for (int p = 0; p < 3; ++p) gWp[p] = (u16*)alloc((size_t)H2_DIM * G_DIM * 2);
  for (int p = 0; p < 3; ++p) h1p[p] = (u16*)alloc((size_t)N_PTS * H1_DIM * 2);
  for (int p = 0; p < 3; ++p) hp[p]  = (u16*)alloc((size_t)N_PTS * H2_DIM * 2);
  float* hF  = (float*)alloc((size_t)N_PTS * H2_DIM * 4);
  float* WhF = (float*)alloc((size_t)N_PTS * G_DIM * 4);
  float* sqv = (float*)alloc(N_PTS * 4);
  float* f1v = (float*)alloc(N_PTS * 4);
  float* f2v = (float*)alloc(N_PTS * 4);
  float* Wc  = (float*)alloc(64 * NOUT * 4);
  float* bc  = (float*)alloc(64 * 4);

  char* pbase = w;
  const size_t MN1 = (size_t)N_PTS * H1_DIM;
  const size_t MN2 = (size_t)N_PTS * H2_DIM;
  const size_t MN3 = (size_t)N_PTS * G_DIM;
  float* P1 = (float*)alloc(4 * MN1 * 4);
  float* P2 = (float*)alloc(4 * MN2 * 4);
  float* P3 = (float*)alloc(4 * MN3 * 4);
  u16* Sb = (u16*)pbase;

  const int TS = D_IN * H1_DIM + H1_DIM * H2_DIM + H2_DIM * G_DIM + 64 * NOUT;
  prep_all<<<(TS + 255) / 256, 256, 0, stream>>>(
      W0, W0p[0], W0p[1], W0p[2], W1, W1p[0], W1p[1], W1p[2], gW, gWp[0], gWp[1], gWp[2],
      cW, cb, dW, db, Wc, bc);

  mfma_gemm<64, true, true, false, false, false, false>
      <<<dim3(H1_DIM / 64, N_PTS / 64, 4), 256, 0, stream>>>(
      x, nullptr, nullptr, W0p[0], W0p[1], W0p[2], nullptr,
      P1, nullptr, nullptr, nullptr, D_IN, D_IN / 4, H1_DIM, MN1);
  combine_s<4><<<(int)(MN1 / 1024), 256, 0, stream>>>(
      P1, b0, MN1, H1_DIM, h1p[0], h1p[1], h1p[2]);

  mfma_gemm<64, false, true, false, false, false, false>
      <<<dim3(H2_DIM / 64, N_PTS / 64, 4), 256, 0, stream>>>(
      h1p[0], h1p[1], h1p[2], W1p[0], W1p[1], W1p[2], nullptr,
      P2, nullptr, nullptr, nullptr, H1_DIM, H1_DIM / 4, H2_DIM, MN2);
  combine_h<<<(int)(MN2 / 1024), 256, 0, stream>>>(
      P2, b1, MN2, hF, hp[0], hp[1], hp[2], sqv);

  mfma_gemm<64, false, true, false, false, false, false>
      <<<dim3(G_DIM / 64, N_PTS / 64, 4), 256, 0, stream>>>(
      hp[0], hp[1], hp[2], gWp[0], gWp[1], gWp[2], nullptr,
      P3, nullptr, nullptr, nullptr, H2_DIM, H2_DIM / 4, G_DIM, MN3);
  combine_wh<<<(int)(MN3 / 1024), 256, 0, stream>>>(
      P3, MN3, WhF, ga, f1v, f2v);

  gram_symm<<<dim3(N_PTS / 128, N_PTS / 128), 512, 0, stream>>>(
      hp[0], hp[1], hp[2], sqv, Sb, N_PTS);
  topk_att<<<N_PTS / 4, 256, 0, stream>>>(Sb, f1v, f2v, WhF, Wc, bc, sqv, hF, out, 0, N_PTS);
}